// Round 1
// 4153.130 us; speedup vs baseline: 1.5445x; 1.5445x over previous
//
#include <hip/hip_runtime.h>
#include <hip/hip_fp16.h>
#include <math.h>

#define B 8
#define M 256
#define D 65536

static constexpr float ALPHA = 0.5f;
static constexpr int N_ITERS = 50;
static constexpr int N_POWER = 10;

// ---------------------------------------------------------------------------
// K0: convert A fp32 -> fp16 (consistent quantization; all later math uses Ah)
// ---------------------------------------------------------------------------
__global__ __launch_bounds__(256) void k_conv(const float* __restrict__ A,
                                              __half* __restrict__ Ah) {
    const size_t n8 = (size_t)B * M * D / 8;  // 16,777,216 groups of 8
    size_t stride = (size_t)gridDim.x * 256;
    for (size_t i = (size_t)blockIdx.x * 256 + threadIdx.x; i < n8; i += stride) {
        float4 f0 = ((const float4*)A)[2 * i];
        float4 f1 = ((const float4*)A)[2 * i + 1];
        union { uint4 u; __half2 h[4]; } o;
        o.h[0] = __floats2half2_rn(f0.x, f0.y);
        o.h[1] = __floats2half2_rn(f0.z, f0.w);
        o.h[2] = __floats2half2_rn(f1.x, f1.y);
        o.h[3] = __floats2half2_rn(f1.z, f1.w);
        ((uint4*)Ah)[i] = o.u;
    }
}

// ---------------------------------------------------------------------------
// K1: y[b,m] = dot(Ah[b,m,:], x[b,:]);  u0[b,m] = rowsum(Ah[b,m,:]) / sqrt(D)
// ---------------------------------------------------------------------------
__global__ __launch_bounds__(256) void k_y_u0(const __half* __restrict__ Ah,
                                              const float* __restrict__ x,
                                              float* __restrict__ y,
                                              float* __restrict__ u) {
    int bm = blockIdx.x;
    int b = bm >> 8;
    const uint4* arow = (const uint4*)(Ah + (size_t)bm * D);
    const float4* xrow = (const float4*)(x + (size_t)b * D);
    float sy = 0.f, ss = 0.f;
#pragma unroll 4
    for (int i = threadIdx.x; i < D / 8; i += 256) {
        uint4 a = arow[i];
        const __half2* hp = (const __half2*)&a;
        float4 x0 = xrow[2 * i], x1 = xrow[2 * i + 1];
        float2 f0 = __half22float2(hp[0]);
        float2 f1 = __half22float2(hp[1]);
        float2 f2 = __half22float2(hp[2]);
        float2 f3 = __half22float2(hp[3]);
        sy += f0.x * x0.x + f0.y * x0.y + f1.x * x0.z + f1.y * x0.w +
              f2.x * x1.x + f2.y * x1.y + f3.x * x1.z + f3.y * x1.w;
        ss += f0.x + f0.y + f1.x + f1.y + f2.x + f2.y + f3.x + f3.y;
    }
    __shared__ float sdata[8];
    for (int off = 32; off > 0; off >>= 1) {
        sy += __shfl_down(sy, off, 64);
        ss += __shfl_down(ss, off, 64);
    }
    int lane = threadIdx.x & 63, wid = threadIdx.x >> 6;
    if (lane == 0) { sdata[wid] = sy; sdata[4 + wid] = ss; }
    __syncthreads();
    if (threadIdx.x == 0) {
        y[bm] = sdata[0] + sdata[1] + sdata[2] + sdata[3];
        u[bm] = (sdata[4] + sdata[5] + sdata[6] + sdata[7]) * 0.00390625f;
    }
}

// ---------------------------------------------------------------------------
// K2: Gram G[b] = Ah[b] * Ah[b]^T (256x256), 64x64 tiles, 16 K-chunks of 4096
// ---------------------------------------------------------------------------
__global__ __launch_bounds__(256) void k_gram(const __half* __restrict__ Ah,
                                              float* __restrict__ G) {
    const int PI[10] = {0, 0, 0, 0, 1, 1, 1, 2, 2, 3};
    const int PJ[10] = {0, 1, 2, 3, 1, 2, 3, 2, 3, 3};
    int idx = blockIdx.x;
    int ch = idx & 15; idx >>= 4;
    int p = idx % 10;
    int b = idx / 10;
    int ti = PI[p] * 64, tj = PJ[p] * 64;
    int k0 = ch * 4096;

    __shared__ __align__(16) float As[16][68];
    __shared__ __align__(16) float Bs[16][68];

    int t = threadIdx.x;
    int lrow = t >> 2;
    int lk = (t & 3) << 2;
    int r0 = (t >> 4) << 2;
    int c0 = (t & 15) << 2;

    const __half* Ab = Ah + (size_t)b * M * D;
    float acc[4][4] = {};

    for (int ks = 0; ks < 4096; ks += 16) {
        uint2 au = *(const uint2*)(Ab + (size_t)(ti + lrow) * D + k0 + ks + lk);
        uint2 bu = *(const uint2*)(Ab + (size_t)(tj + lrow) * D + k0 + ks + lk);
        const __half2* ah = (const __half2*)&au;
        const __half2* bh = (const __half2*)&bu;
        float2 a0 = __half22float2(ah[0]), a1 = __half22float2(ah[1]);
        float2 b0 = __half22float2(bh[0]), b1 = __half22float2(bh[1]);
        __syncthreads();
        As[lk + 0][lrow] = a0.x; As[lk + 1][lrow] = a0.y;
        As[lk + 2][lrow] = a1.x; As[lk + 3][lrow] = a1.y;
        Bs[lk + 0][lrow] = b0.x; Bs[lk + 1][lrow] = b0.y;
        Bs[lk + 2][lrow] = b1.x; Bs[lk + 3][lrow] = b1.y;
        __syncthreads();
#pragma unroll
        for (int k = 0; k < 16; ++k) {
            float4 a = *(const float4*)&As[k][r0];
            float4 c = *(const float4*)&Bs[k][c0];
            float avv[4] = {a.x, a.y, a.z, a.w};
            float cvv[4] = {c.x, c.y, c.z, c.w};
#pragma unroll
            for (int i = 0; i < 4; ++i)
#pragma unroll
                for (int j = 0; j < 4; ++j)
                    acc[i][j] += avv[i] * cvv[j];
        }
    }
    float* Gb = G + (size_t)b * M * M;
    bool offdiag = (ti != tj);
#pragma unroll
    for (int i = 0; i < 4; ++i)
#pragma unroll
        for (int j = 0; j < 4; ++j) {
            atomicAdd(&Gb[(size_t)(ti + r0 + i) * M + (tj + c0 + j)], acc[i][j]);
            if (offdiag)
                atomicAdd(&Gb[(size_t)(tj + c0 + j) * M + (ti + r0 + i)], acc[i][j]);
        }
}

// ---------------------------------------------------------------------------
// K3: power iteration in M-space (G is tiny fp32).
// ---------------------------------------------------------------------------
__global__ __launch_bounds__(256) void k_power(const float* __restrict__ G,
                                               const float* __restrict__ u0,
                                               float* __restrict__ Lp) {
    int b = blockIdx.x;
    int m = threadIdx.x;
    __shared__ float su[M];
    __shared__ float red[4];
    su[m] = u0[b * M + m];
    __syncthreads();
    const float* Gb = G + (size_t)b * M * M;
    for (int it = 0; it < N_POWER; ++it) {
        float gm = 0.f;
        const float4* grow = (const float4*)(Gb + (size_t)m * M);
#pragma unroll 8
        for (int k = 0; k < M / 4; ++k) {
            float4 g = grow[k];
            gm += g.x * su[4 * k] + g.y * su[4 * k + 1] + g.z * su[4 * k + 2] +
                  g.w * su[4 * k + 3];
        }
        float part = su[m] * gm;
        for (int off = 32; off > 0; off >>= 1) part += __shfl_down(part, off, 64);
        if ((m & 63) == 0) red[m >> 6] = part;
        __syncthreads();
        float n = sqrtf(red[0] + red[1] + red[2] + red[3]);
        float inv = 1.f / (n + 1e-12f);
        su[m] = gm * inv;
        __syncthreads();
    }
    float part = su[m] * su[m];
    for (int off = 32; off > 0; off >>= 1) part += __shfl_down(part, off, 64);
    if ((m & 63) == 0) red[m >> 6] = part;
    __syncthreads();
    if (m == 0) {
        float L = (red[0] + red[1] + red[2] + red[3]) * (1.0f / 256.0f);
        Lp[b * 4 + 0] = L;
        Lp[b * 4 + 1] = 1.0f / (256.0f * L);
        Lp[b * 4 + 2] = ALPHA / L;
    }
}

// ---------------------------------------------------------------------------
// K4a (NEW): c[b,m] = (sum_chunk spart[b][chunk][m] - y[b,m]) / (M*L_b)
// spart holds per-chunk partials of A·z from the previous k_fista launch
// (zeros before iteration 0, so c_0 = -y/(M L) as required).
// grid: 64 blocks (b, m-group of 32) x 256 threads (32 m x 8 chunk-groups)
// ---------------------------------------------------------------------------
__global__ __launch_bounds__(256) void k_cstep(const float* __restrict__ spart,
                                               const float* __restrict__ y,
                                               const float* __restrict__ Lp,
                                               float* __restrict__ c) {
    int blk = blockIdx.x;
    int b = blk >> 3;
    int mg = blk & 7;
    int t = threadIdx.x;
    int tm = t & 31;
    int cg = t >> 5;               // 0..7
    int m = mg * 32 + tm;
    const float* sp = spart + (size_t)b * 512 * M + m;
    float s = 0.f;
#pragma unroll 8
    for (int ch = cg; ch < 512; ch += 8)
        s += sp[(size_t)ch * M];
    __shared__ float red[8][32];
    red[cg][tm] = s;
    __syncthreads();
    if (t < 32) {
        float sv = red[0][t] + red[1][t] + red[2][t] + red[3][t] +
                   red[4][t] + red[5][t] + red[6][t] + red[7][t];
        int bm = b * M + mg * 32 + t;
        c[bm] = (sv - y[bm]) * Lp[b * 4 + 1];
    }
}

// ---------------------------------------------------------------------------
// K4b (NEW, fused): single pass over A per iteration.
// Block = (b, 128-column chunk). The 256x128 fp16 tile is loaded ONCE into
// registers (16 x uint4 per thread = 64 VGPR) and used for BOTH matvecs:
//   pass 1: g_d = sum_m A[m,d] c[m]          (A^T c, pre-scaled by 1/(M L))
//   update: w_new = soft(z - g, alpha/L); z_new = w_new + beta (w_new - w_old)
//   pass 2: spart[b][chunk][m] = sum_{d in chunk} A[m,d] z_new_d   (A z_new)
// Thread map: t = mi*16 + dj; thread reads rows m = s*16+mi (s=0..15),
// columns d0 + dj*8 .. +7 (one uint4). 4 rows x 256B per wave-load instr.
// ---------------------------------------------------------------------------
__global__ __launch_bounds__(256) void k_fista(const __half* __restrict__ Ah,
                                               const float* __restrict__ cc,
                                               const float* __restrict__ Lp,
                                               float* __restrict__ z,
                                               float* __restrict__ w,
                                               float* __restrict__ spart,
                                               float beta) {
    int cid = blockIdx.x;
    int b = cid >> 9;
    int chunk = cid & 511;
    int d0 = chunk << 7;           // 128 columns per chunk
    int t = threadIdx.x;
    int dj = t & 15;
    int mi = t >> 4;

    __shared__ float sc[M];        // c vector
    __shared__ float gws[4][16][8];// per-wave g partials
    __shared__ float znS[128];     // z_new for this chunk
    __shared__ float sred[M];      // per-m partial of A z_new

    sc[t] = cc[b * M + t];
    __syncthreads();

    const __half* Ap = Ah + (size_t)b * M * D + (size_t)mi * D + d0 + dj * 8;
    uint4 areg[16];
    float g[8] = {};
#pragma unroll
    for (int s = 0; s < 16; ++s) {
        areg[s] = *(const uint4*)(Ap + (size_t)(s * 16) * D);
        float cm = sc[s * 16 + mi];
        const __half2* hp = (const __half2*)&areg[s];
        float2 f0 = __half22float2(hp[0]);
        float2 f1 = __half22float2(hp[1]);
        float2 f2 = __half22float2(hp[2]);
        float2 f3 = __half22float2(hp[3]);
        g[0] = fmaf(f0.x, cm, g[0]); g[1] = fmaf(f0.y, cm, g[1]);
        g[2] = fmaf(f1.x, cm, g[2]); g[3] = fmaf(f1.y, cm, g[3]);
        g[4] = fmaf(f2.x, cm, g[4]); g[5] = fmaf(f2.y, cm, g[5]);
        g[6] = fmaf(f3.x, cm, g[6]); g[7] = fmaf(f3.y, cm, g[7]);
    }
    // reduce over the wave's 4 mi values (lanes mi_low*16+dj): xor 16, 32
#pragma unroll
    for (int j = 0; j < 8; ++j) {
        g[j] += __shfl_xor(g[j], 16, 64);
        g[j] += __shfl_xor(g[j], 32, 64);
    }
    int wv = t >> 6;
    if ((t & 63) < 16) {           // one lane per dj per wave
#pragma unroll
        for (int j = 0; j < 8; ++j) gws[wv][dj][j] = g[j];
    }
    __syncthreads();

    // 128 threads finish g reduction + soft-threshold update for 128 d's
    if (t < 128) {
        int ldj = t >> 3, lj = t & 7;
        float gs = gws[0][ldj][lj] + gws[1][ldj][lj] +
                   gws[2][ldj][lj] + gws[3][ldj][lj];
        size_t zi = (size_t)b * D + d0 + t;
        float thr = Lp[b * 4 + 2];
        float zv = z[zi], wold = w[zi];
        float cand = zv - gs;
        float a1 = fabsf(cand) - thr;
        float wn = a1 > 0.f ? copysignf(a1, cand) : 0.f;
        float znv = wn + beta * (wn - wold);
        w[zi] = wn;
        z[zi] = znv;
        znS[t] = znv;
    }
    __syncthreads();

    // pass 2: reuse register tile for partial A z_new (per-chunk M-vector)
    float zr[8];
    {
        float4 z0 = *(const float4*)&znS[dj * 8];
        float4 z1 = *(const float4*)&znS[dj * 8 + 4];
        zr[0] = z0.x; zr[1] = z0.y; zr[2] = z0.z; zr[3] = z0.w;
        zr[4] = z1.x; zr[5] = z1.y; zr[6] = z1.z; zr[7] = z1.w;
    }
#pragma unroll
    for (int s = 0; s < 16; ++s) {
        const __half2* hp = (const __half2*)&areg[s];
        float2 f0 = __half22float2(hp[0]);
        float2 f1 = __half22float2(hp[1]);
        float2 f2 = __half22float2(hp[2]);
        float2 f3 = __half22float2(hp[3]);
        float p = f0.x * zr[0] + f0.y * zr[1] + f1.x * zr[2] + f1.y * zr[3] +
                  f2.x * zr[4] + f2.y * zr[5] + f3.x * zr[6] + f3.y * zr[7];
        // reduce over dj (16 contiguous lanes)
        p += __shfl_xor(p, 1, 64);
        p += __shfl_xor(p, 2, 64);
        p += __shfl_xor(p, 4, 64);
        p += __shfl_xor(p, 8, 64);
        if (dj == 0) sred[s * 16 + mi] = p;   // unique (s,mi) per wave: no clash
    }
    __syncthreads();
    spart[((size_t)b * 512 + chunk) * M + t] = sred[t];
}

// ---------------------------------------------------------------------------
extern "C" void kernel_launch(void* const* d_in, const int* in_sizes, int n_in,
                              void* d_out, int out_size, void* d_ws, size_t ws_size,
                              hipStream_t stream) {
    (void)in_sizes; (void)n_in; (void)out_size; (void)ws_size;
    const float* x = (const float*)d_in[0];        // [B, D]
    const float* A = (const float*)d_in[1];        // [B, M, D]
    float* w = (float*)d_out;                      // [B, D]

    // workspace layout: Ah (fp16, 256 MiB) first, fp32 scratch after
    __half* Ah = (__half*)d_ws;
    float* ws = (float*)((char*)d_ws + (size_t)B * M * D * sizeof(__half));
    float* y  = ws;                 // 2048
    float* u  = ws + 2048;          // 2048
    float* Lp = ws + 4096;          // 32
    float* c  = ws + 4128;          // 2048
    float* z  = ws + 8192;          // 524288 (16B aligned)
    float* G  = ws + 8192 + 524288; // 524288 (2 MiB) — dead after k_power
    float* spart = G;               // 1048576 floats (4 MiB), overlaps G

    hipMemsetAsync(G, 0, (size_t)B * M * M * sizeof(float), stream);
    hipMemsetAsync(z, 0, (size_t)B * D * sizeof(float), stream);
    hipMemsetAsync(w, 0, (size_t)B * D * sizeof(float), stream);

    k_conv<<<16384, 256, 0, stream>>>(A, Ah);
    k_y_u0<<<B * M, 256, 0, stream>>>(Ah, x, y, u);
    k_gram<<<B * 10 * 16, 256, 0, stream>>>(Ah, G);
    k_power<<<B, 256, 0, stream>>>(G, u, Lp);

    // spart must be zero before iteration 0 (=> s = A*0 = 0); stream-ordered
    // after k_power since it overlaps G.
    hipMemsetAsync(spart, 0, (size_t)B * 512 * M * sizeof(float), stream);

    double t = 1.0;
    for (int k = 0; k < N_ITERS; ++k) {
        double tn = 0.5 * (1.0 + sqrt(1.0 + 4.0 * t * t));
        float beta = (float)((t - 1.0) / tn);
        k_cstep<<<64, 256, 0, stream>>>(spart, y, Lp, c);
        k_fista<<<B * 512, 256, 0, stream>>>(Ah, c, Lp, z, w, spart, beta);
        t = tn;
    }
}

// Round 2
// 3734.289 us; speedup vs baseline: 1.7178x; 1.1122x over previous
//
#include <hip/hip_runtime.h>
#include <hip/hip_fp16.h>
#include <math.h>

#define B 8
#define M 256
#define D 65536

static constexpr float ALPHA = 0.5f;
static constexpr int N_ITERS = 50;
static constexpr int N_POWER = 10;

typedef _Float16 f16x8 __attribute__((ext_vector_type(8)));
typedef float f32x4 __attribute__((ext_vector_type(4)));

// ---------------------------------------------------------------------------
// K0: convert A fp32 -> fp16 (consistent quantization; all later math uses Ah)
// ---------------------------------------------------------------------------
__global__ __launch_bounds__(256) void k_conv(const float* __restrict__ A,
                                              __half* __restrict__ Ah) {
    const size_t n8 = (size_t)B * M * D / 8;  // 16,777,216 groups of 8
    size_t stride = (size_t)gridDim.x * 256;
    for (size_t i = (size_t)blockIdx.x * 256 + threadIdx.x; i < n8; i += stride) {
        float4 f0 = ((const float4*)A)[2 * i];
        float4 f1 = ((const float4*)A)[2 * i + 1];
        union { uint4 u; __half2 h[4]; } o;
        o.h[0] = __floats2half2_rn(f0.x, f0.y);
        o.h[1] = __floats2half2_rn(f0.z, f0.w);
        o.h[2] = __floats2half2_rn(f1.x, f1.y);
        o.h[3] = __floats2half2_rn(f1.z, f1.w);
        ((uint4*)Ah)[i] = o.u;
    }
}

// ---------------------------------------------------------------------------
// K1: y[b,m] = dot(Ah[b,m,:], x[b,:]);  u0[b,m] = rowsum(Ah[b,m,:]) / sqrt(D)
// ---------------------------------------------------------------------------
__global__ __launch_bounds__(256) void k_y_u0(const __half* __restrict__ Ah,
                                              const float* __restrict__ x,
                                              float* __restrict__ y,
                                              float* __restrict__ u) {
    int bm = blockIdx.x;
    int b = bm >> 8;
    const uint4* arow = (const uint4*)(Ah + (size_t)bm * D);
    const float4* xrow = (const float4*)(x + (size_t)b * D);
    float sy = 0.f, ss = 0.f;
#pragma unroll 4
    for (int i = threadIdx.x; i < D / 8; i += 256) {
        uint4 a = arow[i];
        const __half2* hp = (const __half2*)&a;
        float4 x0 = xrow[2 * i], x1 = xrow[2 * i + 1];
        float2 f0 = __half22float2(hp[0]);
        float2 f1 = __half22float2(hp[1]);
        float2 f2 = __half22float2(hp[2]);
        float2 f3 = __half22float2(hp[3]);
        sy += f0.x * x0.x + f0.y * x0.y + f1.x * x0.z + f1.y * x0.w +
              f2.x * x1.x + f2.y * x1.y + f3.x * x1.z + f3.y * x1.w;
        ss += f0.x + f0.y + f1.x + f1.y + f2.x + f2.y + f3.x + f3.y;
    }
    __shared__ float sdata[8];
    for (int off = 32; off > 0; off >>= 1) {
        sy += __shfl_down(sy, off, 64);
        ss += __shfl_down(ss, off, 64);
    }
    int lane = threadIdx.x & 63, wid = threadIdx.x >> 6;
    if (lane == 0) { sdata[wid] = sy; sdata[4 + wid] = ss; }
    __syncthreads();
    if (threadIdx.x == 0) {
        y[bm] = sdata[0] + sdata[1] + sdata[2] + sdata[3];
        u[bm] = (sdata[4] + sdata[5] + sdata[6] + sdata[7]) * 0.00390625f;
    }
}

// ---------------------------------------------------------------------------
// K2 (MFMA): Gram G[b] = Ah[b] * Ah[b]^T using v_mfma_f32_16x16x32_f16.
// Block = (b, 128-row-block pair p, K-chunk of 2048). 256 thr = 4 waves,
// each wave owns a 64x64 quadrant of the 128x128 C tile as 4x4 16x16 frags.
// Staging: BK=32 via global_load_lds width-16, linear LDS [128][32] halves
// (lane-linear order matches: lane l -> row l>>2, 16B slot l&3).
// Per K-step: 8 ds_read_b128 + 16 MFMA per wave.
// A.A^T: both operands are A rows; B-frag (col c of C) = row (tj+c) of A,
// loaded with the identical k-contiguous pattern as the A-frag.
// ---------------------------------------------------------------------------
__global__ __launch_bounds__(256) void k_gram_mfma(const __half* __restrict__ Ah,
                                                   float* __restrict__ G) {
    int bx = blockIdx.x;
    int ch = bx & 31;              // 32 K-chunks of 2048
    int p  = (bx >> 5) % 3;        // pair: (0,0) (0,128) (128,128)
    int b  = bx / 96;
    const int PI[3] = {0, 0, 128};
    const int PJ[3] = {0, 128, 128};
    int ti = PI[p], tj = PJ[p];
    int k0 = ch * 2048;

    __shared__ __half As[128 * 32];
    __shared__ __half Bs[128 * 32];

    int t = threadIdx.x;
    int w = t >> 6, lane = t & 63;
    int wr = w >> 1, wc = w & 1;   // wave quadrant (row, col)

    const __half* Ab = Ah + (size_t)b * M * D;

    // staging addresses: wave w stages rows [w*32, w*32+32) of As and Bs
    int srow = w * 32 + (lane >> 2);   // + 16 for the second instr
    int scol = (lane & 3) * 8;         // halves within the 32-k slice

    f32x4 acc[4][4];
#pragma unroll
    for (int i = 0; i < 4; ++i)
#pragma unroll
        for (int j = 0; j < 4; ++j)
            acc[i][j] = (f32x4){0.f, 0.f, 0.f, 0.f};

    int frow = lane & 15;          // frag row/col within 16
    int koff = (lane >> 4) * 8;    // 8 contiguous k per lane

    for (int ks = 0; ks < 2048; ks += 32) {
        __syncthreads();  // previous step's ds_reads done before overwrite
        {
            const __half* ga0 = Ab + (size_t)(ti + srow) * D + k0 + ks + scol;
            const __half* ga1 = ga0 + (size_t)16 * D;
            const __half* gb0 = Ab + (size_t)(tj + srow) * D + k0 + ks + scol;
            const __half* gb1 = gb0 + (size_t)16 * D;
            __builtin_amdgcn_global_load_lds(
                (const __attribute__((address_space(1))) void*)ga0,
                (__attribute__((address_space(3))) void*)&As[(w * 32) * 32], 16, 0, 0);
            __builtin_amdgcn_global_load_lds(
                (const __attribute__((address_space(1))) void*)ga1,
                (__attribute__((address_space(3))) void*)&As[(w * 32 + 16) * 32], 16, 0, 0);
            __builtin_amdgcn_global_load_lds(
                (const __attribute__((address_space(1))) void*)gb0,
                (__attribute__((address_space(3))) void*)&Bs[(w * 32) * 32], 16, 0, 0);
            __builtin_amdgcn_global_load_lds(
                (const __attribute__((address_space(1))) void*)gb1,
                (__attribute__((address_space(3))) void*)&Bs[(w * 32 + 16) * 32], 16, 0, 0);
        }
        __syncthreads();  // compiler emits vmcnt(0) drain before barrier

        f16x8 aF[4], bF[4];
#pragma unroll
        for (int i = 0; i < 4; ++i)
            aF[i] = *(const f16x8*)&As[(wr * 64 + i * 16 + frow) * 32 + koff];
#pragma unroll
        for (int j = 0; j < 4; ++j)
            bF[j] = *(const f16x8*)&Bs[(wc * 64 + j * 16 + frow) * 32 + koff];
#pragma unroll
        for (int i = 0; i < 4; ++i)
#pragma unroll
            for (int j = 0; j < 4; ++j)
                acc[i][j] = __builtin_amdgcn_mfma_f32_16x16x32_f16(
                    aF[i], bF[j], acc[i][j], 0, 0, 0);
    }

    // epilogue: C/D layout col=lane&15, row=(lane>>4)*4+reg  (m89/m91)
    float* Gb = G + (size_t)b * M * M;
    bool offd = (ti != tj);
    int r0 = (lane >> 4) * 4;
    int c0 = lane & 15;
#pragma unroll
    for (int i = 0; i < 4; ++i)
#pragma unroll
        for (int j = 0; j < 4; ++j)
#pragma unroll
            for (int r = 0; r < 4; ++r) {
                int gi = ti + wr * 64 + i * 16 + r0 + r;
                int gj = tj + wc * 64 + j * 16 + c0;
                float v = acc[i][j][r];
                atomicAdd(&Gb[(size_t)gi * M + gj], v);
                if (offd) atomicAdd(&Gb[(size_t)gj * M + gi], v);
            }
}

// ---------------------------------------------------------------------------
// K3: power iteration in M-space (G is tiny fp32).
// ---------------------------------------------------------------------------
__global__ __launch_bounds__(256) void k_power(const float* __restrict__ G,
                                               const float* __restrict__ u0,
                                               float* __restrict__ Lp) {
    int b = blockIdx.x;
    int m = threadIdx.x;
    __shared__ float su[M];
    __shared__ float red[4];
    su[m] = u0[b * M + m];
    __syncthreads();
    const float* Gb = G + (size_t)b * M * M;
    for (int it = 0; it < N_POWER; ++it) {
        float gm = 0.f;
        const float4* grow = (const float4*)(Gb + (size_t)m * M);
#pragma unroll 8
        for (int k = 0; k < M / 4; ++k) {
            float4 g = grow[k];
            gm += g.x * su[4 * k] + g.y * su[4 * k + 1] + g.z * su[4 * k + 2] +
                  g.w * su[4 * k + 3];
        }
        float part = su[m] * gm;
        for (int off = 32; off > 0; off >>= 1) part += __shfl_down(part, off, 64);
        if ((m & 63) == 0) red[m >> 6] = part;
        __syncthreads();
        float n = sqrtf(red[0] + red[1] + red[2] + red[3]);
        float inv = 1.f / (n + 1e-12f);
        su[m] = gm * inv;
        __syncthreads();
    }
    float part = su[m] * su[m];
    for (int off = 32; off > 0; off >>= 1) part += __shfl_down(part, off, 64);
    if ((m & 63) == 0) red[m >> 6] = part;
    __syncthreads();
    if (m == 0) {
        float L = (red[0] + red[1] + red[2] + red[3]) * (1.0f / 256.0f);
        Lp[b * 4 + 0] = L;
        Lp[b * 4 + 1] = 1.0f / (256.0f * L);
        Lp[b * 4 + 2] = ALPHA / L;
    }
}

// ---------------------------------------------------------------------------
// K4a: c[b,m] = (sum_chunk spart[b][chunk][m] - y[b,m]) / (M*L_b)
// ---------------------------------------------------------------------------
__global__ __launch_bounds__(256) void k_cstep(const float* __restrict__ spart,
                                               const float* __restrict__ y,
                                               const float* __restrict__ Lp,
                                               float* __restrict__ c) {
    int blk = blockIdx.x;
    int b = blk >> 3;
    int mg = blk & 7;
    int t = threadIdx.x;
    int tm = t & 31;
    int cg = t >> 5;               // 0..7
    int m = mg * 32 + tm;
    const float* sp = spart + (size_t)b * 512 * M + m;
    float s = 0.f;
#pragma unroll 8
    for (int ch = cg; ch < 512; ch += 8)
        s += sp[(size_t)ch * M];
    __shared__ float red[8][32];
    red[cg][tm] = s;
    __syncthreads();
    if (t < 32) {
        float sv = red[0][t] + red[1][t] + red[2][t] + red[3][t] +
                   red[4][t] + red[5][t] + red[6][t] + red[7][t];
        int bm = b * M + mg * 32 + t;
        c[bm] = (sv - y[bm]) * Lp[b * 4 + 1];
    }
}

// ---------------------------------------------------------------------------
// K4b (fused): single pass over A per iteration; register-resident tile used
// for both A^T c and the partial A z_new.
// ---------------------------------------------------------------------------
__global__ __launch_bounds__(256) void k_fista(const __half* __restrict__ Ah,
                                               const float* __restrict__ cc,
                                               const float* __restrict__ Lp,
                                               float* __restrict__ z,
                                               float* __restrict__ w,
                                               float* __restrict__ spart,
                                               float beta) {
    int cid = blockIdx.x;
    int b = cid >> 9;
    int chunk = cid & 511;
    int d0 = chunk << 7;           // 128 columns per chunk
    int t = threadIdx.x;
    int dj = t & 15;
    int mi = t >> 4;

    __shared__ float sc[M];        // c vector
    __shared__ float gws[4][16][8];// per-wave g partials
    __shared__ float znS[128];     // z_new for this chunk
    __shared__ float sred[M];      // per-m partial of A z_new

    sc[t] = cc[b * M + t];
    __syncthreads();

    const __half* Ap = Ah + (size_t)b * M * D + (size_t)mi * D + d0 + dj * 8;
    uint4 areg[16];
    float g[8] = {};
#pragma unroll
    for (int s = 0; s < 16; ++s) {
        areg[s] = *(const uint4*)(Ap + (size_t)(s * 16) * D);
        float cm = sc[s * 16 + mi];
        const __half2* hp = (const __half2*)&areg[s];
        float2 f0 = __half22float2(hp[0]);
        float2 f1 = __half22float2(hp[1]);
        float2 f2 = __half22float2(hp[2]);
        float2 f3 = __half22float2(hp[3]);
        g[0] = fmaf(f0.x, cm, g[0]); g[1] = fmaf(f0.y, cm, g[1]);
        g[2] = fmaf(f1.x, cm, g[2]); g[3] = fmaf(f1.y, cm, g[3]);
        g[4] = fmaf(f2.x, cm, g[4]); g[5] = fmaf(f2.y, cm, g[5]);
        g[6] = fmaf(f3.x, cm, g[6]); g[7] = fmaf(f3.y, cm, g[7]);
    }
#pragma unroll
    for (int j = 0; j < 8; ++j) {
        g[j] += __shfl_xor(g[j], 16, 64);
        g[j] += __shfl_xor(g[j], 32, 64);
    }
    int wv = t >> 6;
    if ((t & 63) < 16) {
#pragma unroll
        for (int j = 0; j < 8; ++j) gws[wv][dj][j] = g[j];
    }
    __syncthreads();

    if (t < 128) {
        int ldj = t >> 3, lj = t & 7;
        float gs = gws[0][ldj][lj] + gws[1][ldj][lj] +
                   gws[2][ldj][lj] + gws[3][ldj][lj];
        size_t zi = (size_t)b * D + d0 + t;
        float thr = Lp[b * 4 + 2];
        float zv = z[zi], wold = w[zi];
        float cand = zv - gs;
        float a1 = fabsf(cand) - thr;
        float wn = a1 > 0.f ? copysignf(a1, cand) : 0.f;
        float znv = wn + beta * (wn - wold);
        w[zi] = wn;
        z[zi] = znv;
        znS[t] = znv;
    }
    __syncthreads();

    float zr[8];
    {
        float4 z0 = *(const float4*)&znS[dj * 8];
        float4 z1 = *(const float4*)&znS[dj * 8 + 4];
        zr[0] = z0.x; zr[1] = z0.y; zr[2] = z0.z; zr[3] = z0.w;
        zr[4] = z1.x; zr[5] = z1.y; zr[6] = z1.z; zr[7] = z1.w;
    }
#pragma unroll
    for (int s = 0; s < 16; ++s) {
        const __half2* hp = (const __half2*)&areg[s];
        float2 f0 = __half22float2(hp[0]);
        float2 f1 = __half22float2(hp[1]);
        float2 f2 = __half22float2(hp[2]);
        float2 f3 = __half22float2(hp[3]);
        float p = f0.x * zr[0] + f0.y * zr[1] + f1.x * zr[2] + f1.y * zr[3] +
                  f2.x * zr[4] + f2.y * zr[5] + f3.x * zr[6] + f3.y * zr[7];
        p += __shfl_xor(p, 1, 64);
        p += __shfl_xor(p, 2, 64);
        p += __shfl_xor(p, 4, 64);
        p += __shfl_xor(p, 8, 64);
        if (dj == 0) sred[s * 16 + mi] = p;
    }
    __syncthreads();
    spart[((size_t)b * 512 + chunk) * M + t] = sred[t];
}

// ---------------------------------------------------------------------------
extern "C" void kernel_launch(void* const* d_in, const int* in_sizes, int n_in,
                              void* d_out, int out_size, void* d_ws, size_t ws_size,
                              hipStream_t stream) {
    (void)in_sizes; (void)n_in; (void)out_size; (void)ws_size;
    const float* x = (const float*)d_in[0];        // [B, D]
    const float* A = (const float*)d_in[1];        // [B, M, D]
    float* w = (float*)d_out;                      // [B, D]

    // workspace layout: Ah (fp16, 256 MiB) first, fp32 scratch after
    __half* Ah = (__half*)d_ws;
    float* ws = (float*)((char*)d_ws + (size_t)B * M * D * sizeof(__half));
    float* y  = ws;                 // 2048
    float* u  = ws + 2048;          // 2048
    float* Lp = ws + 4096;          // 32
    float* c  = ws + 4128;          // 2048
    float* z  = ws + 8192;          // 524288 (16B aligned)
    float* G  = ws + 8192 + 524288; // 524288 (2 MiB) — dead after k_power
    float* spart = G;               // 1048576 floats (4 MiB), overlaps G

    hipMemsetAsync(G, 0, (size_t)B * M * M * sizeof(float), stream);
    hipMemsetAsync(z, 0, (size_t)B * D * sizeof(float), stream);
    hipMemsetAsync(w, 0, (size_t)B * D * sizeof(float), stream);

    k_conv<<<16384, 256, 0, stream>>>(A, Ah);
    k_y_u0<<<B * M, 256, 0, stream>>>(Ah, x, y, u);
    k_gram_mfma<<<8 * 3 * 32, 256, 0, stream>>>(Ah, G);
    k_power<<<B, 256, 0, stream>>>(G, u, Lp);

    // spart must be zero before iteration 0 (=> s = A*0 = 0); stream-ordered
    // after k_power since it overlaps G.
    hipMemsetAsync(spart, 0, (size_t)B * 512 * M * sizeof(float), stream);

    double t = 1.0;
    for (int k = 0; k < N_ITERS; ++k) {
        double tn = 0.5 * (1.0 + sqrt(1.0 + 4.0 * t * t));
        float beta = (float)((t - 1.0) / tn);
        k_cstep<<<64, 256, 0, stream>>>(spart, y, Lp, c);
        k_fista<<<B * 512, 256, 0, stream>>>(Ah, c, Lp, z, w, spart, beta);
        t = tn;
    }
}

// Round 3
// 3706.874 us; speedup vs baseline: 1.7305x; 1.0074x over previous
//
#include <hip/hip_runtime.h>
#include <hip/hip_fp16.h>
#include <math.h>

#define B 8
#define M 256
#define D 65536
#define NCH 512   // D / 128 column-chunks

static constexpr float ALPHA = 0.5f;
static constexpr int N_ITERS = 50;
static constexpr int N_POWER = 10;

typedef _Float16 f16x8 __attribute__((ext_vector_type(8)));
typedef float f32x4 __attribute__((ext_vector_type(4)));

// ---------------------------------------------------------------------------
// Tile-major fp16 layout: Aht[b][ch][m][dlo], ch = d>>7, dlo = d&127.
// A (b,ch) tile is 256 rows x 128 cols = 64 KiB CONTIGUOUS -> every loop
// kernel streams contiguous slabs instead of 256B segments 128 KiB apart.
// ---------------------------------------------------------------------------

// K0: convert A fp32 -> fp16 tile-major. Reads contiguous, writes 256B segs
// (one-time cost).
__global__ __launch_bounds__(256) void k_conv(const float* __restrict__ A,
                                              __half* __restrict__ Aht) {
    const size_t n8 = (size_t)B * M * D / 8;  // 16,777,216 groups of 8
    size_t stride = (size_t)gridDim.x * 256;
    for (size_t i = (size_t)blockIdx.x * 256 + threadIdx.x; i < n8; i += stride) {
        float4 f0 = ((const float4*)A)[2 * i];
        float4 f1 = ((const float4*)A)[2 * i + 1];
        union { uint4 u; __half2 h[4]; } o;
        o.h[0] = __floats2half2_rn(f0.x, f0.y);
        o.h[1] = __floats2half2_rn(f0.z, f0.w);
        o.h[2] = __floats2half2_rn(f1.x, f1.y);
        o.h[3] = __floats2half2_rn(f1.z, f1.w);
        size_t d8 = i & (D / 8 - 1);       // 0..8191
        size_t m  = (i >> 13) & (M - 1);
        size_t b  = i >> 21;
        size_t ch = d8 >> 4;               // 16 groups of 8 per 128-chunk
        size_t dlo8 = d8 & 15;
        ((uint4*)Aht)[(((b * NCH + ch) * M + m) << 4) + dlo8] = o.u;
    }
}

// ---------------------------------------------------------------------------
// K1a: per-(b,ch) partials of y[b,m] = dot(Ah[m,:], x) and rowsum(Ah[m,:]).
// Same streaming structure as k_fista pass 2: block reads 64 KiB contiguous.
// ---------------------------------------------------------------------------
__global__ __launch_bounds__(256) void k_ypart(const __half* __restrict__ Aht,
                                               const float* __restrict__ x,
                                               float* __restrict__ ypart,
                                               float* __restrict__ upart) {
    int cid = blockIdx.x;
    int b = cid >> 9;
    int ch = cid & (NCH - 1);
    int t = threadIdx.x;
    int dj = t & 15;
    int mi = t >> 4;

    __shared__ float xs[128];
    __shared__ float sredY[M];
    __shared__ float sredU[M];
    if (t < 32)
        ((float4*)xs)[t] = ((const float4*)(x + (size_t)b * D + ch * 128))[t];
    __syncthreads();

    float zr[8];
    {
        float4 z0 = *(const float4*)&xs[dj * 8];
        float4 z1 = *(const float4*)&xs[dj * 8 + 4];
        zr[0] = z0.x; zr[1] = z0.y; zr[2] = z0.z; zr[3] = z0.w;
        zr[4] = z1.x; zr[5] = z1.y; zr[6] = z1.z; zr[7] = z1.w;
    }

    const __half* Ap = Aht + (((size_t)b * NCH + ch) * M + mi) * 128 + dj * 8;
#pragma unroll
    for (int s = 0; s < 16; ++s) {
        uint4 a = *(const uint4*)(Ap + (size_t)(s * 16) * 128);
        const __half2* hp = (const __half2*)&a;
        float2 f0 = __half22float2(hp[0]);
        float2 f1 = __half22float2(hp[1]);
        float2 f2 = __half22float2(hp[2]);
        float2 f3 = __half22float2(hp[3]);
        float p = f0.x * zr[0] + f0.y * zr[1] + f1.x * zr[2] + f1.y * zr[3] +
                  f2.x * zr[4] + f2.y * zr[5] + f3.x * zr[6] + f3.y * zr[7];
        float q = f0.x + f0.y + f1.x + f1.y + f2.x + f2.y + f3.x + f3.y;
        p += __shfl_xor(p, 1, 64); q += __shfl_xor(q, 1, 64);
        p += __shfl_xor(p, 2, 64); q += __shfl_xor(q, 2, 64);
        p += __shfl_xor(p, 4, 64); q += __shfl_xor(q, 4, 64);
        p += __shfl_xor(p, 8, 64); q += __shfl_xor(q, 8, 64);
        if (dj == 0) { sredY[s * 16 + mi] = p; sredU[s * 16 + mi] = q; }
    }
    __syncthreads();
    ypart[((size_t)b * NCH + ch) * M + t] = sredY[t];
    upart[((size_t)b * NCH + ch) * M + t] = sredU[t];
}

// K1b: y[b,m] = sum_ch ypart; u[b,m] = sum_ch upart / 256
__global__ __launch_bounds__(256) void k_yred(const float* __restrict__ ypart,
                                              const float* __restrict__ upart,
                                              float* __restrict__ y,
                                              float* __restrict__ u) {
    int blk = blockIdx.x;          // 64 = B * 8
    int b = blk >> 3;
    int mg = blk & 7;
    int t = threadIdx.x;
    int tm = t & 31;
    int cg = t >> 5;
    int m = mg * 32 + tm;
    const float* yp = ypart + (size_t)b * NCH * M + m;
    const float* up = upart + (size_t)b * NCH * M + m;
    float sy = 0.f, su = 0.f;
#pragma unroll 8
    for (int ch = cg; ch < NCH; ch += 8) {
        sy += yp[(size_t)ch * M];
        su += up[(size_t)ch * M];
    }
    __shared__ float redY[8][32], redU[8][32];
    redY[cg][tm] = sy; redU[cg][tm] = su;
    __syncthreads();
    if (t < 32) {
        float vy = 0.f, vu = 0.f;
#pragma unroll
        for (int g = 0; g < 8; ++g) { vy += redY[g][t]; vu += redU[g][t]; }
        int bm = b * M + mg * 32 + t;
        y[bm] = vy;
        u[bm] = vu * 0.00390625f;
    }
}

// ---------------------------------------------------------------------------
// K2 (MFMA): Gram G[b] = Ah[b] * Ah[b]^T using v_mfma_f32_16x16x32_f16.
// Tile-major addressing: a 32-k staging window lies inside one 128-chunk;
// rows are 256B apart (whole sub-tile contiguous -> better L2 locality).
// ---------------------------------------------------------------------------
__global__ __launch_bounds__(256) void k_gram_mfma(const __half* __restrict__ Aht,
                                                   float* __restrict__ G) {
    int bx = blockIdx.x;
    int ch2 = bx & 31;             // 32 K-chunks of 2048
    int p  = (bx >> 5) % 3;        // pair: (0,0) (0,128) (128,128)
    int b  = bx / 96;
    const int PI[3] = {0, 0, 128};
    const int PJ[3] = {0, 128, 128};
    int ti = PI[p], tj = PJ[p];
    int k0 = ch2 * 2048;

    __shared__ __half As[128 * 32];
    __shared__ __half Bs[128 * 32];

    int t = threadIdx.x;
    int w = t >> 6, lane = t & 63;
    int wr = w >> 1, wc = w & 1;

    // staging: wave w stages rows [w*32, w*32+32)
    int srow = w * 32 + (lane >> 2);
    int scol = (lane & 3) * 8;

    f32x4 acc[4][4];
#pragma unroll
    for (int i = 0; i < 4; ++i)
#pragma unroll
        for (int j = 0; j < 4; ++j)
            acc[i][j] = (f32x4){0.f, 0.f, 0.f, 0.f};

    int frow = lane & 15;
    int koff = (lane >> 4) * 8;

    const size_t bbase = (size_t)b * NCH;
    for (int ks = 0; ks < 2048; ks += 32) {
        int d = k0 + ks;
        size_t chb = bbase + (d >> 7);
        int dlo = d & 127;
        __syncthreads();  // previous step's ds_reads done before overwrite
        {
            const __half* ga0 = Aht + (chb * M + (ti + srow)) * 128 + dlo + scol;
            const __half* ga1 = ga0 + 16 * 128;
            const __half* gb0 = Aht + (chb * M + (tj + srow)) * 128 + dlo + scol;
            const __half* gb1 = gb0 + 16 * 128;
            __builtin_amdgcn_global_load_lds(
                (const __attribute__((address_space(1))) void*)ga0,
                (__attribute__((address_space(3))) void*)&As[(w * 32) * 32], 16, 0, 0);
            __builtin_amdgcn_global_load_lds(
                (const __attribute__((address_space(1))) void*)ga1,
                (__attribute__((address_space(3))) void*)&As[(w * 32 + 16) * 32], 16, 0, 0);
            __builtin_amdgcn_global_load_lds(
                (const __attribute__((address_space(1))) void*)gb0,
                (__attribute__((address_space(3))) void*)&Bs[(w * 32) * 32], 16, 0, 0);
            __builtin_amdgcn_global_load_lds(
                (const __attribute__((address_space(1))) void*)gb1,
                (__attribute__((address_space(3))) void*)&Bs[(w * 32 + 16) * 32], 16, 0, 0);
        }
        __syncthreads();

        f16x8 aF[4], bF[4];
#pragma unroll
        for (int i = 0; i < 4; ++i)
            aF[i] = *(const f16x8*)&As[(wr * 64 + i * 16 + frow) * 32 + koff];
#pragma unroll
        for (int j = 0; j < 4; ++j)
            bF[j] = *(const f16x8*)&Bs[(wc * 64 + j * 16 + frow) * 32 + koff];
#pragma unroll
        for (int i = 0; i < 4; ++i)
#pragma unroll
            for (int j = 0; j < 4; ++j)
                acc[i][j] = __builtin_amdgcn_mfma_f32_16x16x32_f16(
                    aF[i], bF[j], acc[i][j], 0, 0, 0);
    }

    // epilogue: C/D layout col=lane&15, row=(lane>>4)*4+reg
    float* Gb = G + (size_t)b * M * M;
    bool offd = (ti != tj);
    int r0 = (lane >> 4) * 4;
    int c0 = lane & 15;
#pragma unroll
    for (int i = 0; i < 4; ++i)
#pragma unroll
        for (int j = 0; j < 4; ++j)
#pragma unroll
            for (int r = 0; r < 4; ++r) {
                int gi = ti + wr * 64 + i * 16 + r0 + r;
                int gj = tj + wc * 64 + j * 16 + c0;
                float v = acc[i][j][r];
                atomicAdd(&Gb[(size_t)gi * M + gj], v);
                if (offd) atomicAdd(&Gb[(size_t)gj * M + gi], v);
            }
}

// ---------------------------------------------------------------------------
// K3: power iteration in M-space (G is tiny fp32).
// ---------------------------------------------------------------------------
__global__ __launch_bounds__(256) void k_power(const float* __restrict__ G,
                                               const float* __restrict__ u0,
                                               float* __restrict__ Lp) {
    int b = blockIdx.x;
    int m = threadIdx.x;
    __shared__ float su[M];
    __shared__ float red[4];
    su[m] = u0[b * M + m];
    __syncthreads();
    const float* Gb = G + (size_t)b * M * M;
    for (int it = 0; it < N_POWER; ++it) {
        float gm = 0.f;
        const float4* grow = (const float4*)(Gb + (size_t)m * M);
#pragma unroll 8
        for (int k = 0; k < M / 4; ++k) {
            float4 g = grow[k];
            gm += g.x * su[4 * k] + g.y * su[4 * k + 1] + g.z * su[4 * k + 2] +
                  g.w * su[4 * k + 3];
        }
        float part = su[m] * gm;
        for (int off = 32; off > 0; off >>= 1) part += __shfl_down(part, off, 64);
        if ((m & 63) == 0) red[m >> 6] = part;
        __syncthreads();
        float n = sqrtf(red[0] + red[1] + red[2] + red[3]);
        float inv = 1.f / (n + 1e-12f);
        su[m] = gm * inv;
        __syncthreads();
    }
    float part = su[m] * su[m];
    for (int off = 32; off > 0; off >>= 1) part += __shfl_down(part, off, 64);
    if ((m & 63) == 0) red[m >> 6] = part;
    __syncthreads();
    if (m == 0) {
        float L = (red[0] + red[1] + red[2] + red[3]) * (1.0f / 256.0f);
        Lp[b * 4 + 0] = L;
        Lp[b * 4 + 1] = 1.0f / (256.0f * L);
        Lp[b * 4 + 2] = ALPHA / L;
    }
}

// ---------------------------------------------------------------------------
// K4a: c[b,m] = (sum_chunk spart[b][chunk][m] - y[b,m]) / (M*L_b)
// ---------------------------------------------------------------------------
__global__ __launch_bounds__(256) void k_cstep(const float* __restrict__ spart,
                                               const float* __restrict__ y,
                                               const float* __restrict__ Lp,
                                               float* __restrict__ c) {
    int blk = blockIdx.x;
    int b = blk >> 3;
    int mg = blk & 7;
    int t = threadIdx.x;
    int tm = t & 31;
    int cg = t >> 5;               // 0..7
    int m = mg * 32 + tm;
    const float* sp = spart + (size_t)b * NCH * M + m;
    float s = 0.f;
#pragma unroll 8
    for (int ch = cg; ch < NCH; ch += 8)
        s += sp[(size_t)ch * M];
    __shared__ float red[8][32];
    red[cg][tm] = s;
    __syncthreads();
    if (t < 32) {
        float sv = red[0][t] + red[1][t] + red[2][t] + red[3][t] +
                   red[4][t] + red[5][t] + red[6][t] + red[7][t];
        int bm = b * M + mg * 32 + t;
        c[bm] = (sv - y[bm]) * Lp[b * 4 + 1];
    }
}

// ---------------------------------------------------------------------------
// K4b (fused): single pass over A per iteration; register-resident tile used
// for both A^T c and the partial A z_new. Tile-major: block reads 64 KiB
// contiguous (byte offset == t*16 per s-step).
// ---------------------------------------------------------------------------
__global__ __launch_bounds__(256) void k_fista(const __half* __restrict__ Aht,
                                               const float* __restrict__ cc,
                                               const float* __restrict__ Lp,
                                               float* __restrict__ z,
                                               float* __restrict__ w,
                                               float* __restrict__ spart,
                                               float beta) {
    int cid = blockIdx.x;
    int b = cid >> 9;
    int chunk = cid & (NCH - 1);
    int d0 = chunk << 7;           // 128 columns per chunk
    int t = threadIdx.x;
    int dj = t & 15;
    int mi = t >> 4;

    __shared__ float sc[M];        // c vector
    __shared__ float gws[4][16][8];// per-wave g partials
    __shared__ float znS[128];     // z_new for this chunk
    __shared__ float sred[M];      // per-m partial of A z_new

    sc[t] = cc[b * M + t];
    __syncthreads();

    const __half* Ap = Aht + (((size_t)b * NCH + chunk) * M + mi) * 128 + dj * 8;
    uint4 areg[16];
    float g[8] = {};
#pragma unroll
    for (int s = 0; s < 16; ++s) {
        areg[s] = *(const uint4*)(Ap + (size_t)(s * 16) * 128);
        float cm = sc[s * 16 + mi];
        const __half2* hp = (const __half2*)&areg[s];
        float2 f0 = __half22float2(hp[0]);
        float2 f1 = __half22float2(hp[1]);
        float2 f2 = __half22float2(hp[2]);
        float2 f3 = __half22float2(hp[3]);
        g[0] = fmaf(f0.x, cm, g[0]); g[1] = fmaf(f0.y, cm, g[1]);
        g[2] = fmaf(f1.x, cm, g[2]); g[3] = fmaf(f1.y, cm, g[3]);
        g[4] = fmaf(f2.x, cm, g[4]); g[5] = fmaf(f2.y, cm, g[5]);
        g[6] = fmaf(f3.x, cm, g[6]); g[7] = fmaf(f3.y, cm, g[7]);
    }
#pragma unroll
    for (int j = 0; j < 8; ++j) {
        g[j] += __shfl_xor(g[j], 16, 64);
        g[j] += __shfl_xor(g[j], 32, 64);
    }
    int wv = t >> 6;
    if ((t & 63) < 16) {
#pragma unroll
        for (int j = 0; j < 8; ++j) gws[wv][dj][j] = g[j];
    }
    __syncthreads();

    if (t < 128) {
        int ldj = t >> 3, lj = t & 7;
        float gs = gws[0][ldj][lj] + gws[1][ldj][lj] +
                   gws[2][ldj][lj] + gws[3][ldj][lj];
        size_t zi = (size_t)b * D + d0 + t;
        float thr = Lp[b * 4 + 2];
        float zv = z[zi], wold = w[zi];
        float cand = zv - gs;
        float a1 = fabsf(cand) - thr;
        float wn = a1 > 0.f ? copysignf(a1, cand) : 0.f;
        float znv = wn + beta * (wn - wold);
        w[zi] = wn;
        z[zi] = znv;
        znS[t] = znv;
    }
    __syncthreads();

    float zr[8];
    {
        float4 z0 = *(const float4*)&znS[dj * 8];
        float4 z1 = *(const float4*)&znS[dj * 8 + 4];
        zr[0] = z0.x; zr[1] = z0.y; zr[2] = z0.z; zr[3] = z0.w;
        zr[4] = z1.x; zr[5] = z1.y; zr[6] = z1.z; zr[7] = z1.w;
    }
#pragma unroll
    for (int s = 0; s < 16; ++s) {
        const __half2* hp = (const __half2*)&areg[s];
        float2 f0 = __half22float2(hp[0]);
        float2 f1 = __half22float2(hp[1]);
        float2 f2 = __half22float2(hp[2]);
        float2 f3 = __half22float2(hp[3]);
        float p = f0.x * zr[0] + f0.y * zr[1] + f1.x * zr[2] + f1.y * zr[3] +
                  f2.x * zr[4] + f2.y * zr[5] + f3.x * zr[6] + f3.y * zr[7];
        p += __shfl_xor(p, 1, 64);
        p += __shfl_xor(p, 2, 64);
        p += __shfl_xor(p, 4, 64);
        p += __shfl_xor(p, 8, 64);
        if (dj == 0) sred[s * 16 + mi] = p;
    }
    __syncthreads();
    spart[((size_t)b * NCH + chunk) * M + t] = sred[t];
}

// ---------------------------------------------------------------------------
extern "C" void kernel_launch(void* const* d_in, const int* in_sizes, int n_in,
                              void* d_out, int out_size, void* d_ws, size_t ws_size,
                              hipStream_t stream) {
    (void)in_sizes; (void)n_in; (void)out_size; (void)ws_size;
    const float* x = (const float*)d_in[0];        // [B, D]
    const float* A = (const float*)d_in[1];        // [B, M, D]
    float* w = (float*)d_out;                      // [B, D]

    // workspace layout: Aht (fp16 tile-major, 256 MiB) first, fp32 after
    __half* Aht = (__half*)d_ws;
    float* ws = (float*)((char*)d_ws + (size_t)B * M * D * sizeof(__half));
    float* y  = ws;                 // 2048
    float* u  = ws + 2048;          // 2048
    float* Lp = ws + 4096;          // 32
    float* c  = ws + 4128;          // 2048
    float* z  = ws + 8192;          // 524288 floats (2 MiB)
    float* G  = ws + 8192 + 524288; // 65536 floats  (overlapped by spart)
    float* spart = G;               // B*NCH*M = 1048576 floats (4 MiB)
    float* ypart = spart + (size_t)B * NCH * M;   // 4 MiB
    float* upart = ypart + (size_t)B * NCH * M;   // 4 MiB

    hipMemsetAsync(G, 0, (size_t)B * M * M * sizeof(float), stream);
    hipMemsetAsync(z, 0, (size_t)B * D * sizeof(float), stream);
    hipMemsetAsync(w, 0, (size_t)B * D * sizeof(float), stream);

    k_conv<<<16384, 256, 0, stream>>>(A, Aht);
    k_ypart<<<B * NCH, 256, 0, stream>>>(Aht, x, ypart, upart);
    k_yred<<<64, 256, 0, stream>>>(ypart, upart, y, u);
    k_gram_mfma<<<8 * 3 * 32, 256, 0, stream>>>(Aht, G);
    k_power<<<B, 256, 0, stream>>>(G, u, Lp);

    // spart must be zero before iteration 0 (=> s = A*0 = 0); stream-ordered
    // after k_power since it overlaps G.
    hipMemsetAsync(spart, 0, (size_t)B * NCH * M * sizeof(float), stream);

    double t = 1.0;
    for (int k = 0; k < N_ITERS; ++k) {
        double tn = 0.5 * (1.0 + sqrt(1.0 + 4.0 * t * t));
        float beta = (float)((t - 1.0) / tn);
        k_cstep<<<64, 256, 0, stream>>>(spart, y, Lp, c);
        k_fista<<<B * NCH, 256, 0, stream>>>(Aht, c, Lp, z, w, spart, beta);
        t = tn;
    }
}